// Round 2
// baseline (235.839 us; speedup 1.0000x reference)
//
#include <hip/hip_runtime.h>
#include <math.h>

#define LDIM 4096
#define CDIM 64
#define NB 4
#define TL 64
#define NBLK (LDIM / TL)          // 64 L-tiles per batch
#define EPS 1e-5f

// workspace layout (float offsets) — total ~12.7 MB
#define K_OFF 0                                   // k: [B][C][L]
#define Y_OFF (NB * CDIM * LDIM)                  // y: [B][C][L]
#define P_OFF (2 * NB * CDIM * LDIM)              // M partials: [B*NBLK][C*C]
#define M_OFF (P_OFF + NB * NBLK * CDIM * CDIM)   // M: [B][C*C]
#define S_OFF (M_OFF + NB * CDIM * CDIM)          // BN sums: [2][C]

// ---------------------------------------------------------------------------
// Kernel 1: ELU -> circular conv3 -> QKV -> (k to global, partial M = v q^T)
// grid (NBLK, NB), block 512 (8 waves; each wave owns 8 output channels)
// ---------------------------------------------------------------------------
__global__ __launch_bounds__(512) void k_front(
    const float* __restrict__ x,
    const float* __restrict__ conv_w, const float* __restrict__ conv_b,
    const float* __restrict__ wq, const float* __restrict__ bq,
    const float* __restrict__ wk, const float* __restrict__ bk,
    const float* __restrict__ wv, const float* __restrict__ bv,
    float* __restrict__ k_ws, float* __restrict__ P_ws)
{
    __shared__ float xe[CDIM][TL + 2];   // elu(x) tile; reused as h tile
    __shared__ float qs[CDIM][TL + 1];   // q tile (pad 65 -> <=2-way conflicts, free)
    __shared__ float vs[CDIM][TL + 1];   // v tile

    const int b    = blockIdx.y;
    const int l0   = blockIdx.x * TL;
    const int tid  = threadIdx.x;
    const int lane = tid & 63;
    const int wid  = tid >> 6;                       // wave 0..7
    const int c0   = __builtin_amdgcn_readfirstlane(wid * 8);  // wave-uniform

    const float* xb = x + (size_t)b * CDIM * LDIM;

    // P1: load x tile with circular halo, apply ELU
    for (int idx = tid; idx < CDIM * (TL + 2); idx += 512) {
        int i   = idx / (TL + 2);
        int col = idx - i * (TL + 2);
        int l   = (l0 + col - 1 + LDIM) & (LDIM - 1);
        float t = xb[i * LDIM + l];
        xe[i][col] = t > 0.f ? t : expm1f(t);
    }
    __syncthreads();

    // P2: conv3 (circular). lane = position, wave covers 8 out-channels.
    float hacc[8];
#pragma unroll
    for (int j = 0; j < 8; ++j) hacc[j] = conv_b[c0 + j];

    for (int i = 0; i < CDIM; ++i) {
        float a0 = xe[i][lane], a1 = xe[i][lane + 1], a2 = xe[i][lane + 2];
        const float* wp = conv_w + (c0 * CDIM + i) * 3;   // wave-uniform -> s_load
#pragma unroll
        for (int j = 0; j < 8; ++j) {
            const float* wpj = wp + j * (CDIM * 3);
            hacc[j] = fmaf(wpj[0], a0, fmaf(wpj[1], a1, fmaf(wpj[2], a2, hacc[j])));
        }
    }
    __syncthreads();               // all conv reads of xe complete
#pragma unroll
    for (int j = 0; j < 8; ++j) xe[c0 + j][lane] = hacc[j];   // h tile
    __syncthreads();

    // P3: QKV. h for this position cached in registers.
    float h[CDIM];
#pragma unroll
    for (int i = 0; i < CDIM; ++i) h[i] = xe[i][lane];

#pragma unroll
    for (int j = 0; j < 8; ++j) {       // q
        const float4* wr = (const float4*)(wq + (c0 + j) * CDIM);  // uniform -> s_load_dwordx4
        float a = bq[c0 + j];
#pragma unroll
        for (int i4 = 0; i4 < 16; ++i4) {
            float4 w4 = wr[i4];
            a = fmaf(w4.x, h[i4 * 4 + 0], a);
            a = fmaf(w4.y, h[i4 * 4 + 1], a);
            a = fmaf(w4.z, h[i4 * 4 + 2], a);
            a = fmaf(w4.w, h[i4 * 4 + 3], a);
        }
        qs[c0 + j][lane] = a;
    }
#pragma unroll
    for (int j = 0; j < 8; ++j) {       // k -> global (coalesced per wave)
        const float4* wr = (const float4*)(wk + (c0 + j) * CDIM);
        float a = bk[c0 + j];
#pragma unroll
        for (int i4 = 0; i4 < 16; ++i4) {
            float4 w4 = wr[i4];
            a = fmaf(w4.x, h[i4 * 4 + 0], a);
            a = fmaf(w4.y, h[i4 * 4 + 1], a);
            a = fmaf(w4.z, h[i4 * 4 + 2], a);
            a = fmaf(w4.w, h[i4 * 4 + 3], a);
        }
        k_ws[((size_t)b * CDIM + c0 + j) * LDIM + l0 + lane] = a;
    }
#pragma unroll
    for (int j = 0; j < 8; ++j) {       // v
        const float4* wr = (const float4*)(wv + (c0 + j) * CDIM);
        float a = bv[c0 + j];
#pragma unroll
        for (int i4 = 0; i4 < 16; ++i4) {
            float4 w4 = wr[i4];
            a = fmaf(w4.x, h[i4 * 4 + 0], a);
            a = fmaf(w4.y, h[i4 * 4 + 1], a);
            a = fmaf(w4.z, h[i4 * 4 + 2], a);
            a = fmaf(w4.w, h[i4 * 4 + 3], a);
        }
        vs[c0 + j][lane] = a;
    }
    __syncthreads();

    // P4: partial M[c][c'] = sum_l v[c][l]*q[c'][l]; thread owns a 2x4 tile.
    // No atomics: each block stores its 64x64 partial to a private slot.
    const int cv0 = (tid >> 4) * 2;   // 0..62 step 2
    const int cq0 = (tid & 15) * 4;   // 0..60 step 4
    float m[2][4] = {{0.f, 0.f, 0.f, 0.f}, {0.f, 0.f, 0.f, 0.f}};
    for (int l = 0; l < TL; ++l) {
        float vv[2], qq[4];
#pragma unroll
        for (int i = 0; i < 2; ++i) vv[i] = vs[cv0 + i][l];
#pragma unroll
        for (int j = 0; j < 4; ++j) qq[j] = qs[cq0 + j][l];
#pragma unroll
        for (int i = 0; i < 2; ++i)
#pragma unroll
            for (int j = 0; j < 4; ++j) m[i][j] = fmaf(vv[i], qq[j], m[i][j]);
    }
    float4* Pb = (float4*)(P_ws + ((size_t)b * NBLK + blockIdx.x) * CDIM * CDIM);
#pragma unroll
    for (int i = 0; i < 2; ++i)
        Pb[(cv0 + i) * (CDIM / 4) + (cq0 >> 2)] =
            make_float4(m[i][0], m[i][1], m[i][2], m[i][3]);
}

// ---------------------------------------------------------------------------
// Kernel 1b: reduce partials -> M[b][c][c'].  16 blocks x 256 threads;
// thread owns one float4 of M, sums 64 block-partials (coalesced, L2-hot).
// ---------------------------------------------------------------------------
__global__ __launch_bounds__(256) void k_reduceM(
    const float* __restrict__ P_ws, float* __restrict__ M_ws)
{
    const int b  = blockIdx.x >> 2;                       // 4 blocks per batch
    const int e4 = (blockIdx.x & 3) * 256 + threadIdx.x;  // 0..1023 float4 idx
    const float4* Pf4 = (const float4*)P_ws + (size_t)b * NBLK * (CDIM * CDIM / 4);
    float4 s = make_float4(0.f, 0.f, 0.f, 0.f);
    for (int blk = 0; blk < NBLK; ++blk) {
        float4 p = Pf4[(size_t)blk * (CDIM * CDIM / 4) + e4];
        s.x += p.x; s.y += p.y; s.z += p.z; s.w += p.w;
    }
    ((float4*)M_ws)[(size_t)b * (CDIM * CDIM / 4) + e4] = s;
}

// ---------------------------------------------------------------------------
// Kernel 2: y = M k + x (residual); per-channel BN partial sums via atomics
// (exactly one atomic per channel per block = minimal contention, G12)
// grid (NBLK, NB), block 512
// ---------------------------------------------------------------------------
__global__ __launch_bounds__(512) void k_spatial(
    const float* __restrict__ x, const float* __restrict__ k_ws,
    const float* __restrict__ M_ws, float* __restrict__ y_ws,
    float* __restrict__ sums)
{
    __shared__ float kl[CDIM][TL];
    const int b    = blockIdx.y;
    const int l0   = blockIdx.x * TL;
    const int tid  = threadIdx.x;
    const int lane = tid & 63;
    const int wid  = tid >> 6;
    const int c0   = __builtin_amdgcn_readfirstlane(wid * 8);

    for (int idx = tid; idx < CDIM * TL; idx += 512) {
        int i = idx >> 6, col = idx & 63;
        kl[i][col] = k_ws[((size_t)b * CDIM + i) * LDIM + l0 + col];
    }
    __syncthreads();

    float kr[CDIM];
#pragma unroll
    for (int i = 0; i < CDIM; ++i) kr[i] = kl[i][lane];   // 2-way LDS alias: free

    const float* Mb = M_ws + (size_t)b * CDIM * CDIM;
    float acc[8];
#pragma unroll
    for (int j = 0; j < 8; ++j)
        acc[j] = x[((size_t)b * CDIM + c0 + j) * LDIM + l0 + lane];

#pragma unroll
    for (int j = 0; j < 8; ++j) {
        const float4* mr = (const float4*)(Mb + (c0 + j) * CDIM);  // uniform -> s_load
        float a = acc[j];
#pragma unroll
        for (int i4 = 0; i4 < 16; ++i4) {
            float4 m4 = mr[i4];
            a = fmaf(m4.x, kr[i4 * 4 + 0], a);
            a = fmaf(m4.y, kr[i4 * 4 + 1], a);
            a = fmaf(m4.z, kr[i4 * 4 + 2], a);
            a = fmaf(m4.w, kr[i4 * 4 + 3], a);
        }
        acc[j] = a;
    }

#pragma unroll
    for (int j = 0; j < 8; ++j)
        y_ws[((size_t)b * CDIM + c0 + j) * LDIM + l0 + lane] = acc[j];

    // per-channel partial sums: butterfly over the 64-lane wave
#pragma unroll
    for (int j = 0; j < 8; ++j) {
        float s = acc[j], s2 = acc[j] * acc[j];
        for (int off = 32; off; off >>= 1) {
            s  += __shfl_down(s, off);
            s2 += __shfl_down(s2, off);
        }
        if (lane == 0) {
            atomicAdd(&sums[c0 + j], s);
            atomicAdd(&sums[CDIM + c0 + j], s2);
        }
    }
}

// ---------------------------------------------------------------------------
// Kernel 3: BatchNorm1d (training stats) applied elementwise, float4
// ---------------------------------------------------------------------------
__global__ __launch_bounds__(256) void k_norm(
    const float* __restrict__ y_ws, const float* __restrict__ sums,
    const float* __restrict__ gamma, const float* __restrict__ beta,
    float* __restrict__ out)
{
    const int idx = blockIdx.x * 256 + threadIdx.x;        // float4 index
    const int c   = (idx >> 10) & (CDIM - 1);              // 1024 float4 per (b,c) row
    const float inv = 1.f / (float)(NB * LDIM);
    float s    = sums[c];
    float s2   = sums[CDIM + c];
    float mean = s * inv;
    float var  = fmaf(-mean, mean, s2 * inv);
    float rstd = 1.f / sqrtf(var + EPS);
    float g    = gamma[c] * rstd;
    float bb   = fmaf(-mean, g, beta[c]);

    float4 v = ((const float4*)y_ws)[idx];
    float4 o;
    o.x = fmaf(v.x, g, bb);
    o.y = fmaf(v.y, g, bb);
    o.z = fmaf(v.z, g, bb);
    o.w = fmaf(v.w, g, bb);
    ((float4*)out)[idx] = o;
}

// ---------------------------------------------------------------------------
extern "C" void kernel_launch(void* const* d_in, const int* in_sizes, int n_in,
                              void* d_out, int out_size, void* d_ws, size_t ws_size,
                              hipStream_t stream)
{
    const float* x      = (const float*)d_in[0];
    const float* conv_w = (const float*)d_in[1];
    const float* conv_b = (const float*)d_in[2];
    const float* wq     = (const float*)d_in[3];
    const float* bq     = (const float*)d_in[4];
    const float* wk     = (const float*)d_in[5];
    const float* bk     = (const float*)d_in[6];
    const float* wv     = (const float*)d_in[7];
    const float* bv     = (const float*)d_in[8];
    const float* gamma  = (const float*)d_in[9];
    const float* beta   = (const float*)d_in[10];

    float* ws   = (float*)d_ws;
    float* k_ws = ws + K_OFF;
    float* y_ws = ws + Y_OFF;
    float* P_ws = ws + P_OFF;
    float* M_ws = ws + M_OFF;
    float* sums = ws + S_OFF;

    // ws is re-poisoned to 0xAA before every timed call: zero BN accumulators.
    hipMemsetAsync(sums, 0, 2 * CDIM * sizeof(float), stream);

    dim3 grid(NBLK, NB);
    k_front<<<grid, 512, 0, stream>>>(x, conv_w, conv_b, wq, bq, wk, bk,
                                      wv, bv, k_ws, P_ws);
    k_reduceM<<<16, 256, 0, stream>>>(P_ws, M_ws);
    k_spatial<<<grid, 512, 0, stream>>>(x, k_ws, M_ws, y_ws, sums);

    const int n4 = NB * CDIM * LDIM / 4;
    k_norm<<<n4 / 256, 256, 0, stream>>>(y_ws, sums, gamma, beta, (float*)d_out);
}

// Round 3
// 225.661 us; speedup vs baseline: 1.0451x; 1.0451x over previous
//
#include <hip/hip_runtime.h>
#include <math.h>

#define LDIM 4096
#define CDIM 64
#define NB 4
#define TL 64
#define NBLK (LDIM / TL)          // 64 L-tiles per batch
#define EPS 1e-5f

// workspace layout (float offsets) — total ~12.7 MB
#define K_OFF 0                                   // k: [B][C][L]
#define Y_OFF (NB * CDIM * LDIM)                  // y: [B][C][L]
#define P_OFF (2 * NB * CDIM * LDIM)              // M partials: [B*NBLK][C*C]
#define M_OFF (P_OFF + NB * NBLK * CDIM * CDIM)   // M: [B][C*C]
#define S_OFF (M_OFF + NB * CDIM * CDIM)          // BN sums: [2][C]

// ---------------------------------------------------------------------------
// Kernel 1: ELU -> circular conv3 -> QKV -> (k to global, partial M = v q^T)
// grid (NBLK, NB), block 512 (8 waves; each wave owns 8 output channels).
// NO per-thread arrays >8 elements: stream over i with {1 ds_read_b32 +
// uniform-weight FMAs}. Weights are wave-uniform (c0 readfirstlane'd) ->
// scalar loads, off the VALU/LDS critical path.
// ---------------------------------------------------------------------------
__global__ __launch_bounds__(512, 2) void k_front(
    const float* __restrict__ x,
    const float* __restrict__ conv_w, const float* __restrict__ conv_b,
    const float* __restrict__ wq, const float* __restrict__ bq,
    const float* __restrict__ wk, const float* __restrict__ bk,
    const float* __restrict__ wv, const float* __restrict__ bv,
    float* __restrict__ k_ws, float* __restrict__ P_ws)
{
    __shared__ float xe[CDIM][TL + 2];   // elu(x) tile (halo)
    __shared__ float hs[CDIM][TL + 1];   // conv output tile
    __shared__ float qs[CDIM][TL + 1];   // q tile
    __shared__ float vs[CDIM][TL + 1];   // v tile

    const int b    = blockIdx.y;
    const int l0   = blockIdx.x * TL;
    const int tid  = threadIdx.x;
    const int lane = tid & 63;
    const int wid  = tid >> 6;                                  // wave 0..7
    const int c0   = __builtin_amdgcn_readfirstlane(wid * 8);   // wave-uniform

    const float* xb = x + (size_t)b * CDIM * LDIM;

    // P1: load x tile with circular halo, apply ELU
    for (int idx = tid; idx < CDIM * (TL + 2); idx += 512) {
        int i   = idx / (TL + 2);
        int col = idx - i * (TL + 2);
        int l   = (l0 + col - 1 + LDIM) & (LDIM - 1);
        float t = xb[i * LDIM + l];
        xe[i][col] = t > 0.f ? t : expm1f(t);
    }
    __syncthreads();

    // P2: conv3 (circular). lane = position; wave covers 8 out-channels.
    float hacc[8];
#pragma unroll
    for (int j = 0; j < 8; ++j) hacc[j] = conv_b[c0 + j];

    for (int i = 0; i < CDIM; ++i) {
        float a0 = xe[i][lane], a1 = xe[i][lane + 1], a2 = xe[i][lane + 2];
        const float* wp = conv_w + (c0 * CDIM + i) * 3;   // wave-uniform
#pragma unroll
        for (int j = 0; j < 8; ++j) {
            const float* wpj = wp + j * (CDIM * 3);
            hacc[j] = fmaf(wpj[0], a0, fmaf(wpj[1], a1, fmaf(wpj[2], a2, hacc[j])));
        }
    }
    __syncthreads();
#pragma unroll
    for (int j = 0; j < 8; ++j) hs[c0 + j][lane] = hacc[j];
    __syncthreads();

    // P3: QKV fused — stream h[i] from LDS once, 24 FMAs per i.
    float qa[8], ka[8], va[8];
#pragma unroll
    for (int j = 0; j < 8; ++j) {
        qa[j] = bq[c0 + j];
        ka[j] = bk[c0 + j];
        va[j] = bv[c0 + j];
    }
    for (int i = 0; i < CDIM; ++i) {
        float hv = hs[i][lane];                 // conflict-free b32
        const float* wqr = wq + c0 * CDIM + i;  // wave-uniform -> s_load
        const float* wkr = wk + c0 * CDIM + i;
        const float* wvr = wv + c0 * CDIM + i;
#pragma unroll
        for (int j = 0; j < 8; ++j) {
            qa[j] = fmaf(wqr[j * CDIM], hv, qa[j]);
            ka[j] = fmaf(wkr[j * CDIM], hv, ka[j]);
            va[j] = fmaf(wvr[j * CDIM], hv, va[j]);
        }
    }
#pragma unroll
    for (int j = 0; j < 8; ++j) {
        qs[c0 + j][lane] = qa[j];
        vs[c0 + j][lane] = va[j];
        k_ws[((size_t)b * CDIM + c0 + j) * LDIM + l0 + lane] = ka[j];
    }
    __syncthreads();

    // P4: partial M[c][c'] = sum_l v[c][l]*q[c'][l]; thread owns a 2x4 tile.
    // Each block stores its 64x64 partial to a private slot (no atomics).
    const int cv0 = (tid >> 4) * 2;   // 0..62 step 2
    const int cq0 = (tid & 15) * 4;   // 0..60 step 4
    float m[2][4] = {{0.f, 0.f, 0.f, 0.f}, {0.f, 0.f, 0.f, 0.f}};
    for (int l = 0; l < TL; ++l) {
        float vv0 = vs[cv0][l], vv1 = vs[cv0 + 1][l];
        float q0 = qs[cq0][l], q1 = qs[cq0 + 1][l];
        float q2 = qs[cq0 + 2][l], q3 = qs[cq0 + 3][l];
        m[0][0] = fmaf(vv0, q0, m[0][0]); m[0][1] = fmaf(vv0, q1, m[0][1]);
        m[0][2] = fmaf(vv0, q2, m[0][2]); m[0][3] = fmaf(vv0, q3, m[0][3]);
        m[1][0] = fmaf(vv1, q0, m[1][0]); m[1][1] = fmaf(vv1, q1, m[1][1]);
        m[1][2] = fmaf(vv1, q2, m[1][2]); m[1][3] = fmaf(vv1, q3, m[1][3]);
    }
    float4* Pb = (float4*)(P_ws + ((size_t)b * NBLK + blockIdx.x) * CDIM * CDIM);
#pragma unroll
    for (int i = 0; i < 2; ++i)
        Pb[(cv0 + i) * (CDIM / 4) + (cq0 >> 2)] =
            make_float4(m[i][0], m[i][1], m[i][2], m[i][3]);
}

// ---------------------------------------------------------------------------
// Kernel 1b: reduce partials -> M[b][c][c'].  16 blocks x 256 threads.
// ---------------------------------------------------------------------------
__global__ __launch_bounds__(256) void k_reduceM(
    const float* __restrict__ P_ws, float* __restrict__ M_ws)
{
    const int b  = blockIdx.x >> 2;                       // 4 blocks per batch
    const int e4 = (blockIdx.x & 3) * 256 + threadIdx.x;  // 0..1023 float4 idx
    const float4* Pf4 = (const float4*)P_ws + (size_t)b * NBLK * (CDIM * CDIM / 4);
    float4 s = make_float4(0.f, 0.f, 0.f, 0.f);
    for (int blk = 0; blk < NBLK; ++blk) {
        float4 p = Pf4[(size_t)blk * (CDIM * CDIM / 4) + e4];
        s.x += p.x; s.y += p.y; s.z += p.z; s.w += p.w;
    }
    ((float4*)M_ws)[(size_t)b * (CDIM * CDIM / 4) + e4] = s;
}

// ---------------------------------------------------------------------------
// Kernel 2: y = M k + x (residual); BN partial sums (1 atomic/channel/block).
// Streams k[i] from LDS; M rows are wave-uniform float4 loads (s_load).
// grid (NBLK, NB), block 512
// ---------------------------------------------------------------------------
__global__ __launch_bounds__(512, 2) void k_spatial(
    const float* __restrict__ x, const float* __restrict__ k_ws,
    const float* __restrict__ M_ws, float* __restrict__ y_ws,
    float* __restrict__ sums)
{
    __shared__ float kl[CDIM][TL];
    const int b    = blockIdx.y;
    const int l0   = blockIdx.x * TL;
    const int tid  = threadIdx.x;
    const int lane = tid & 63;
    const int wid  = tid >> 6;
    const int c0   = __builtin_amdgcn_readfirstlane(wid * 8);

    for (int idx = tid; idx < CDIM * TL; idx += 512) {
        int i = idx >> 6, col = idx & 63;
        kl[i][col] = k_ws[((size_t)b * CDIM + i) * LDIM + l0 + col];
    }
    __syncthreads();

    const float* Mb = M_ws + (size_t)b * CDIM * CDIM;
    float acc[8];
#pragma unroll
    for (int j = 0; j < 8; ++j)
        acc[j] = x[((size_t)b * CDIM + c0 + j) * LDIM + l0 + lane];

    for (int i4 = 0; i4 < 16; ++i4) {
        float kv0 = kl[i4 * 4 + 0][lane];       // conflict-free b32
        float kv1 = kl[i4 * 4 + 1][lane];
        float kv2 = kl[i4 * 4 + 2][lane];
        float kv3 = kl[i4 * 4 + 3][lane];
#pragma unroll
        for (int j = 0; j < 8; ++j) {
            float4 m4 = ((const float4*)(Mb + (c0 + j) * CDIM))[i4];  // uniform
            float a = acc[j];
            a = fmaf(m4.x, kv0, a);
            a = fmaf(m4.y, kv1, a);
            a = fmaf(m4.z, kv2, a);
            a = fmaf(m4.w, kv3, a);
            acc[j] = a;
        }
    }

#pragma unroll
    for (int j = 0; j < 8; ++j)
        y_ws[((size_t)b * CDIM + c0 + j) * LDIM + l0 + lane] = acc[j];

    // per-channel partial sums: butterfly over the 64-lane wave
#pragma unroll
    for (int j = 0; j < 8; ++j) {
        float s = acc[j], s2 = acc[j] * acc[j];
        for (int off = 32; off; off >>= 1) {
            s  += __shfl_down(s, off);
            s2 += __shfl_down(s2, off);
        }
        if (lane == 0) {
            atomicAdd(&sums[c0 + j], s);
            atomicAdd(&sums[CDIM + c0 + j], s2);
        }
    }
}

// ---------------------------------------------------------------------------
// Kernel 3: BatchNorm1d (training stats) applied elementwise, float4
// ---------------------------------------------------------------------------
__global__ __launch_bounds__(256) void k_norm(
    const float* __restrict__ y_ws, const float* __restrict__ sums,
    const float* __restrict__ gamma, const float* __restrict__ beta,
    float* __restrict__ out)
{
    const int idx = blockIdx.x * 256 + threadIdx.x;        // float4 index
    const int c   = (idx >> 10) & (CDIM - 1);              // 1024 float4 per (b,c) row
    const float inv = 1.f / (float)(NB * LDIM);
    float s    = sums[c];
    float s2   = sums[CDIM + c];
    float mean = s * inv;
    float var  = fmaf(-mean, mean, s2 * inv);
    float rstd = 1.f / sqrtf(var + EPS);
    float g    = gamma[c] * rstd;
    float bb   = fmaf(-mean, g, beta[c]);

    float4 v = ((const float4*)y_ws)[idx];
    float4 o;
    o.x = fmaf(v.x, g, bb);
    o.y = fmaf(v.y, g, bb);
    o.z = fmaf(v.z, g, bb);
    o.w = fmaf(v.w, g, bb);
    ((float4*)out)[idx] = o;
}

// ---------------------------------------------------------------------------
extern "C" void kernel_launch(void* const* d_in, const int* in_sizes, int n_in,
                              void* d_out, int out_size, void* d_ws, size_t ws_size,
                              hipStream_t stream)
{
    const float* x      = (const float*)d_in[0];
    const float* conv_w = (const float*)d_in[1];
    const float* conv_b = (const float*)d_in[2];
    const float* wq     = (const float*)d_in[3];
    const float* bq     = (const float*)d_in[4];
    const float* wk     = (const float*)d_in[5];
    const float* bk     = (const float*)d_in[6];
    const float* wv     = (const float*)d_in[7];
    const float* bv     = (const float*)d_in[8];
    const float* gamma  = (const float*)d_in[9];
    const float* beta   = (const float*)d_in[10];

    float* ws   = (float*)d_ws;
    float* k_ws = ws + K_OFF;
    float* y_ws = ws + Y_OFF;
    float* P_ws = ws + P_OFF;
    float* M_ws = ws + M_OFF;
    float* sums = ws + S_OFF;

    // ws is re-poisoned to 0xAA before every timed call: zero BN accumulators.
    hipMemsetAsync(sums, 0, 2 * CDIM * sizeof(float), stream);

    dim3 grid(NBLK, NB);
    k_front<<<grid, 512, 0, stream>>>(x, conv_w, conv_b, wq, bq, wk, bk,
                                      wv, bv, k_ws, P_ws);
    k_reduceM<<<16, 256, 0, stream>>>(P_ws, M_ws);
    k_spatial<<<grid, 512, 0, stream>>>(x, k_ws, M_ws, y_ws, sums);

    const int n4 = NB * CDIM * LDIM / 4;
    k_norm<<<n4 / 256, 256, 0, stream>>>(y_ws, sums, gamma, beta, (float*)d_out);
}

// Round 4
// 162.579 us; speedup vs baseline: 1.4506x; 1.3880x over previous
//
#include <hip/hip_runtime.h>
#include <math.h>

#define LDIM 4096
#define CDIM 64
#define NB 4
#define TL 64
#define NBLK (LDIM / TL)          // 64 L-tiles per batch
#define NBLOCKS (NB * NBLK)       // 256
#define EPS 1e-5f

// workspace layout (float offsets) — total ~12.9 MB
#define K_OFF 0                                   // k: [B][C][L]
#define Y_OFF (NB * CDIM * LDIM)                  // y: [B][C][L]
#define P_OFF (2 * NB * CDIM * LDIM)              // M partials: [NBLOCKS][C*C]
#define M_OFF (P_OFF + NBLOCKS * CDIM * CDIM)     // M: [B][C*C]
#define CW_OFF (M_OFF + NB * CDIM * CDIM)         // conv_w transposed: 16*64*16
#define SP_OFF (CW_OFF + 16 * CDIM * 16)          // BN partials: [NBLOCKS][2*C]
#define S_OFF (SP_OFF + NBLOCKS * 2 * CDIM)       // reduced BN sums: [2*C]

// ---------------------------------------------------------------------------
// Kernel 0: transpose conv_w [c][i][3] -> cwT [i4][c][di][4] (pad to float4,
// 16B-aligned rows) so k_front can load weights as aligned dwordx4 VMEM.
// ---------------------------------------------------------------------------
__global__ __launch_bounds__(256) void k_prep(
    const float* __restrict__ cw, float* __restrict__ cwT)
{
    int idx = blockIdx.x * 256 + threadIdx.x;      // 0..16383
    int t  = idx & 3;
    int di = (idx >> 2) & 3;
    int c  = (idx >> 4) & 63;
    int i4 = idx >> 10;
    float v = (t < 3) ? cw[(c * CDIM + i4 * 4 + di) * 3 + t] : 0.f;
    cwT[idx] = v;
}

// ---------------------------------------------------------------------------
// Kernel 1: ELU -> circular conv3 -> QKV -> (k to global, partial M = v q^T)
// grid (NBLK, NB), block 512 (8 waves; wave wid owns out-channels wid*8..+7).
// ALL in-loop operand loads are per-lane VMEM float4 (addresses kept in
// VGPRs — NO readfirstlane), so they pipeline under vmcnt instead of
// serializing as s_load chains (the R2/R3 107µs failure mode).
// ---------------------------------------------------------------------------
__global__ __launch_bounds__(512, 2) void k_front(
    const float* __restrict__ x,
    const float* __restrict__ cwT, const float* __restrict__ conv_b,
    const float* __restrict__ wq, const float* __restrict__ bq,
    const float* __restrict__ wk, const float* __restrict__ bk,
    const float* __restrict__ wv, const float* __restrict__ bv,
    float* __restrict__ k_ws, float* __restrict__ P_ws)
{
    __shared__ float xe[CDIM][TL + 2];   // elu(x) tile + halo
    __shared__ float hs[CDIM][TL + 1];   // conv output, pad 65 (bank-clean)
    __shared__ float qsT[TL][68];        // q transposed [l][c], pad 68
    __shared__ float vsT[TL][68];        // v transposed [l][c]

    const int b    = blockIdx.y;
    const int l0   = blockIdx.x * TL;
    const int tid  = threadIdx.x;
    const int lane = tid & 63;
    const int wid  = tid >> 6;           // divergent value -> c0 stays in VGPR
    const int c0   = wid * 8;

    const float* xb = x + (size_t)b * CDIM * LDIM;

    // P1: load x tile with circular halo, apply ELU
    for (int idx = tid; idx < CDIM * (TL + 2); idx += 512) {
        int i   = idx / (TL + 2);
        int col = idx - i * (TL + 2);
        int l   = (l0 + col - 1 + LDIM) & (LDIM - 1);
        float t = xb[i * LDIM + l];
        xe[i][col] = t > 0.f ? t : expm1f(t);
    }
    __syncthreads();

    // P2: conv3. lane = position; weights as aligned float4 VMEM per i4-chunk.
    const float4* cw4 = (const float4*)cwT;     // [(i4*64 + c)*4 + di]
    float hacc[8];
#pragma unroll
    for (int j = 0; j < 8; ++j) hacc[j] = conv_b[c0 + j];

    for (int i4 = 0; i4 < 16; ++i4) {
        const int i0 = i4 * 4;
        float xv[12];
#pragma unroll
        for (int di = 0; di < 4; ++di) {
            xv[di * 3 + 0] = xe[i0 + di][lane];
            xv[di * 3 + 1] = xe[i0 + di][lane + 1];
            xv[di * 3 + 2] = xe[i0 + di][lane + 2];
        }
#pragma unroll
        for (int jg = 0; jg < 2; ++jg) {
            float4 w[4][4];
#pragma unroll
            for (int jj = 0; jj < 4; ++jj)
#pragma unroll
                for (int di = 0; di < 4; ++di)
                    w[jj][di] = cw4[((size_t)(i4 * 64 + c0 + jg * 4 + jj)) * 4 + di];
#pragma unroll
            for (int jj = 0; jj < 4; ++jj) {
                float a = hacc[jg * 4 + jj];
#pragma unroll
                for (int di = 0; di < 4; ++di)
                    a = fmaf(w[jj][di].x, xv[di * 3 + 0],
                        fmaf(w[jj][di].y, xv[di * 3 + 1],
                        fmaf(w[jj][di].z, xv[di * 3 + 2], a)));
                hacc[jg * 4 + jj] = a;
            }
        }
    }
    __syncthreads();                     // xe reads done
#pragma unroll
    for (int j = 0; j < 8; ++j) hs[c0 + j][lane] = hacc[j];
    __syncthreads();

    // P3: QKV. Weight rows as aligned float4 VMEM; h streamed from LDS.
    const float4* wq4 = (const float4*)wq;
    const float4* wk4 = (const float4*)wk;
    const float4* wv4 = (const float4*)wv;
    float qa[8], ka[8], va[8];
#pragma unroll
    for (int j = 0; j < 8; ++j) {
        qa[j] = bq[c0 + j];
        ka[j] = bk[c0 + j];
        va[j] = bv[c0 + j];
    }
    for (int i4 = 0; i4 < 16; ++i4) {
        float h4[4];
#pragma unroll
        for (int di = 0; di < 4; ++di) h4[di] = hs[i4 * 4 + di][lane];
#pragma unroll
        for (int jg = 0; jg < 2; ++jg) {
            float4 aq[4], ak[4], av[4];
#pragma unroll
            for (int jj = 0; jj < 4; ++jj) {
                int c = c0 + jg * 4 + jj;
                aq[jj] = wq4[c * 16 + i4];
                ak[jj] = wk4[c * 16 + i4];
                av[jj] = wv4[c * 16 + i4];
            }
#pragma unroll
            for (int jj = 0; jj < 4; ++jj) {
                int j = jg * 4 + jj;
                qa[j] = fmaf(aq[jj].x, h4[0], fmaf(aq[jj].y, h4[1],
                        fmaf(aq[jj].z, h4[2], fmaf(aq[jj].w, h4[3], qa[j]))));
                ka[j] = fmaf(ak[jj].x, h4[0], fmaf(ak[jj].y, h4[1],
                        fmaf(ak[jj].z, h4[2], fmaf(ak[jj].w, h4[3], ka[j]))));
                va[j] = fmaf(av[jj].x, h4[0], fmaf(av[jj].y, h4[1],
                        fmaf(av[jj].z, h4[2], fmaf(av[jj].w, h4[3], va[j]))));
            }
        }
    }
#pragma unroll
    for (int j = 0; j < 8; ++j) {
        qsT[lane][c0 + j] = qa[j];       // bank (lane*68+c)%32: 8-way, once
        vsT[lane][c0 + j] = va[j];
        k_ws[((size_t)b * CDIM + c0 + j) * LDIM + l0 + lane] = ka[j];
    }
    __syncthreads();

    // P4: partial M[c][c'] = sum_l v[c][l]*q[c'][l]; thread owns 2x4 tile.
    // Transposed LDS -> 1 b64 + 1 b128 per l, bank-clean.
    const int cv0 = (tid >> 4) * 2;   // 0..62 step 2 (even -> 8B aligned)
    const int cq0 = (tid & 15) * 4;   // 0..60 step 4 (16B aligned)
    float m[2][4] = {{0.f, 0.f, 0.f, 0.f}, {0.f, 0.f, 0.f, 0.f}};
    for (int l = 0; l < TL; ++l) {
        const float2 vv = *reinterpret_cast<const float2*>(&vsT[l][cv0]);
        const float4 qq = *reinterpret_cast<const float4*>(&qsT[l][cq0]);
        m[0][0] = fmaf(vv.x, qq.x, m[0][0]); m[0][1] = fmaf(vv.x, qq.y, m[0][1]);
        m[0][2] = fmaf(vv.x, qq.z, m[0][2]); m[0][3] = fmaf(vv.x, qq.w, m[0][3]);
        m[1][0] = fmaf(vv.y, qq.x, m[1][0]); m[1][1] = fmaf(vv.y, qq.y, m[1][1]);
        m[1][2] = fmaf(vv.y, qq.z, m[1][2]); m[1][3] = fmaf(vv.y, qq.w, m[1][3]);
    }
    float4* Pb = (float4*)(P_ws + ((size_t)b * NBLK + blockIdx.x) * CDIM * CDIM);
#pragma unroll
    for (int i = 0; i < 2; ++i)
        Pb[(cv0 + i) * (CDIM / 4) + (cq0 >> 2)] =
            make_float4(m[i][0], m[i][1], m[i][2], m[i][3]);
}

// ---------------------------------------------------------------------------
// Kernel 1b: reduce partials -> M[b][c][c'].  16 blocks x 256 threads.
// ---------------------------------------------------------------------------
__global__ __launch_bounds__(256) void k_reduceM(
    const float* __restrict__ P_ws, float* __restrict__ M_ws)
{
    const int b  = blockIdx.x >> 2;
    const int e4 = (blockIdx.x & 3) * 256 + threadIdx.x;
    const float4* Pf4 = (const float4*)P_ws + (size_t)b * NBLK * (CDIM * CDIM / 4);
    float4 s = make_float4(0.f, 0.f, 0.f, 0.f);
    for (int blk = 0; blk < NBLK; ++blk) {
        float4 p = Pf4[(size_t)blk * (CDIM * CDIM / 4) + e4];
        s.x += p.x; s.y += p.y; s.z += p.z; s.w += p.w;
    }
    ((float4*)M_ws)[(size_t)b * (CDIM * CDIM / 4) + e4] = s;
}

// ---------------------------------------------------------------------------
// Kernel 2: y = M k + x; BN partial sums -> global (no atomics).
// M rows loaded as per-lane VMEM float4 (VGPR addresses -> pipelined).
// grid (NBLK, NB), block 512
// ---------------------------------------------------------------------------
__global__ __launch_bounds__(512, 2) void k_spatial(
    const float* __restrict__ x, const float* __restrict__ k_ws,
    const float* __restrict__ M_ws, float* __restrict__ y_ws,
    float* __restrict__ spB)
{
    __shared__ float kl[CDIM][TL + 1];   // pad 65, bank-clean
    const int b    = blockIdx.y;
    const int l0   = blockIdx.x * TL;
    const int tid  = threadIdx.x;
    const int lane = tid & 63;
    const int wid  = tid >> 6;           // divergent -> VGPR
    const int c0   = wid * 8;

    for (int idx = tid; idx < CDIM * TL; idx += 512) {
        int i = idx >> 6, col = idx & 63;
        kl[i][col] = k_ws[((size_t)b * CDIM + i) * LDIM + l0 + col];
    }
    __syncthreads();

    const float* Mb = M_ws + (size_t)b * CDIM * CDIM;
    float acc[8];
#pragma unroll
    for (int j = 0; j < 8; ++j)
        acc[j] = x[((size_t)b * CDIM + c0 + j) * LDIM + l0 + lane];

    for (int i4 = 0; i4 < 16; ++i4) {
        float kv0 = kl[i4 * 4 + 0][lane];
        float kv1 = kl[i4 * 4 + 1][lane];
        float kv2 = kl[i4 * 4 + 2][lane];
        float kv3 = kl[i4 * 4 + 3][lane];
#pragma unroll
        for (int j = 0; j < 8; ++j) {
            float4 m4 = ((const float4*)(Mb + (c0 + j) * CDIM))[i4];  // VMEM
            float a = acc[j];
            a = fmaf(m4.x, kv0, a);
            a = fmaf(m4.y, kv1, a);
            a = fmaf(m4.z, kv2, a);
            a = fmaf(m4.w, kv3, a);
            acc[j] = a;
        }
    }

#pragma unroll
    for (int j = 0; j < 8; ++j)
        y_ws[((size_t)b * CDIM + c0 + j) * LDIM + l0 + lane] = acc[j];

    // per-channel partial sums -> per-block slot (two-stage, no atomics)
    const int blk = blockIdx.y * NBLK + blockIdx.x;
#pragma unroll
    for (int j = 0; j < 8; ++j) {
        float s = acc[j], s2 = acc[j] * acc[j];
        for (int off = 32; off; off >>= 1) {
            s  += __shfl_down(s, off);
            s2 += __shfl_down(s2, off);
        }
        if (lane == 0) {
            spB[(size_t)blk * (2 * CDIM) + c0 + j] = s;
            spB[(size_t)blk * (2 * CDIM) + CDIM + c0 + j] = s2;
        }
    }
}

// ---------------------------------------------------------------------------
// Kernel 2b: reduce BN partials. 1 block x 128 threads, coalesced.
// ---------------------------------------------------------------------------
__global__ __launch_bounds__(128) void k_reduceS(
    const float* __restrict__ spB, float* __restrict__ sums)
{
    const int t = threadIdx.x;           // 0..127
    float s0 = 0.f, s1 = 0.f, s2 = 0.f, s3 = 0.f;
    for (int r = 0; r < NBLOCKS; r += 4) {
        s0 += spB[(r + 0) * (2 * CDIM) + t];
        s1 += spB[(r + 1) * (2 * CDIM) + t];
        s2 += spB[(r + 2) * (2 * CDIM) + t];
        s3 += spB[(r + 3) * (2 * CDIM) + t];
    }
    sums[t] = (s0 + s1) + (s2 + s3);
}

// ---------------------------------------------------------------------------
// Kernel 3: BatchNorm1d (training stats) applied elementwise, float4
// ---------------------------------------------------------------------------
__global__ __launch_bounds__(256) void k_norm(
    const float* __restrict__ y_ws, const float* __restrict__ sums,
    const float* __restrict__ gamma, const float* __restrict__ beta,
    float* __restrict__ out)
{
    const int idx = blockIdx.x * 256 + threadIdx.x;        // float4 index
    const int c   = (idx >> 10) & (CDIM - 1);
    const float inv = 1.f / (float)(NB * LDIM);
    float s    = sums[c];
    float s2   = sums[CDIM + c];
    float mean = s * inv;
    float var  = fmaf(-mean, mean, s2 * inv);
    float rstd = 1.f / sqrtf(var + EPS);
    float g    = gamma[c] * rstd;
    float bb   = fmaf(-mean, g, beta[c]);

    float4 v = ((const float4*)y_ws)[idx];
    float4 o;
    o.x = fmaf(v.x, g, bb);
    o.y = fmaf(v.y, g, bb);
    o.z = fmaf(v.z, g, bb);
    o.w = fmaf(v.w, g, bb);
    ((float4*)out)[idx] = o;
}

// ---------------------------------------------------------------------------
extern "C" void kernel_launch(void* const* d_in, const int* in_sizes, int n_in,
                              void* d_out, int out_size, void* d_ws, size_t ws_size,
                              hipStream_t stream)
{
    const float* x      = (const float*)d_in[0];
    const float* conv_w = (const float*)d_in[1];
    const float* conv_b = (const float*)d_in[2];
    const float* wq     = (const float*)d_in[3];
    const float* bq     = (const float*)d_in[4];
    const float* wk     = (const float*)d_in[5];
    const float* bk     = (const float*)d_in[6];
    const float* wv     = (const float*)d_in[7];
    const float* bv     = (const float*)d_in[8];
    const float* gamma  = (const float*)d_in[9];
    const float* beta   = (const float*)d_in[10];

    float* ws   = (float*)d_ws;
    float* k_ws = ws + K_OFF;
    float* y_ws = ws + Y_OFF;
    float* P_ws = ws + P_OFF;
    float* M_ws = ws + M_OFF;
    float* cwT  = ws + CW_OFF;
    float* spB  = ws + SP_OFF;
    float* sums = ws + S_OFF;

    dim3 grid(NBLK, NB);
    k_prep<<<64, 256, 0, stream>>>(conv_w, cwT);
    k_front<<<grid, 512, 0, stream>>>(x, cwT, conv_b, wq, bq, wk, bk,
                                      wv, bv, k_ws, P_ws);
    k_reduceM<<<16, 256, 0, stream>>>(P_ws, M_ws);
    k_spatial<<<grid, 512, 0, stream>>>(x, k_ws, M_ws, y_ws, spB);
    k_reduceS<<<1, 128, 0, stream>>>(spB, sums);

    const int n4 = NB * CDIM * LDIM / 4;
    k_norm<<<n4 / 256, 256, 0, stream>>>(y_ws, sums, gamma, beta, (float*)d_out);
}

// Round 5
// 159.434 us; speedup vs baseline: 1.4792x; 1.0197x over previous
//
#include <hip/hip_runtime.h>
#include <math.h>

#define LDIM 4096
#define CDIM 64
#define NB 4
#define TL 64
#define NBLK (LDIM / TL)          // 64 L-tiles per batch
#define NBLOCKS (NB * NBLK)       // 256
#define EPS 1e-5f

// workspace layout (float offsets) — total ~12.9 MB
#define K_OFF 0                                   // k: [B][C][L]
#define Y_OFF (NB * CDIM * LDIM)                  // y: [B][C][L]
#define P_OFF (2 * NB * CDIM * LDIM)              // M partials: [NBLOCKS][C*C]
#define M_OFF (P_OFF + NBLOCKS * CDIM * CDIM)     // M: [B][C*C]
#define CW_OFF (M_OFF + NB * CDIM * CDIM)         // conv_w transposed: 16*64*16
#define SP_OFF (CW_OFF + 16 * CDIM * 16)          // BN partials: [NBLOCKS][2*C]
#define S_OFF (SP_OFF + NBLOCKS * 2 * CDIM)       // reduced BN sums: [2*C]

// ---------------------------------------------------------------------------
// Kernel 0: transpose conv_w [c][i][3] -> cwT [i4][c][di][4] (pad to float4)
// ---------------------------------------------------------------------------
__global__ __launch_bounds__(256) void k_prep(
    const float* __restrict__ cw, float* __restrict__ cwT)
{
    int idx = blockIdx.x * 256 + threadIdx.x;      // 0..16383
    int t  = idx & 3;
    int di = (idx >> 2) & 3;
    int c  = (idx >> 4) & 63;
    int i4 = idx >> 10;
    float v = (t < 3) ? cw[(c * CDIM + i4 * 4 + di) * 3 + t] : 0.f;
    cwT[idx] = v;
}

// ---------------------------------------------------------------------------
// Kernel 1: ELU -> circular conv3 -> QKV -> (k to global, partial M = v q^T)
// grid (NBLK, NB), block 1024 = 16 waves; wave owns 4 out-channels.
// 16 waves/CU (50% occupancy) to hide the L2 latency of the per-lane VMEM
// weight loads (R4: 8 waves/CU -> VALUBusy 20%, latency-bound).
// ---------------------------------------------------------------------------
__global__ __launch_bounds__(1024, 4) void k_front(
    const float* __restrict__ x,
    const float* __restrict__ cwT, const float* __restrict__ conv_b,
    const float* __restrict__ wq, const float* __restrict__ bq,
    const float* __restrict__ wk, const float* __restrict__ bk,
    const float* __restrict__ wv, const float* __restrict__ bv,
    float* __restrict__ k_ws, float* __restrict__ P_ws)
{
    __shared__ float xe[CDIM][TL + 2];               // elu(x) tile + halo
    __shared__ float hs[CDIM][TL + 1];               // conv output
    __shared__ alignas(16) float qsT[TL][68];        // q transposed [l][c]
    __shared__ alignas(16) float vsT[TL][68];        // v transposed [l][c]

    const int b    = blockIdx.y;
    const int l0   = blockIdx.x * TL;
    const int tid  = threadIdx.x;
    const int lane = tid & 63;
    const int wid  = tid >> 6;           // 0..15 (divergent value -> VGPR)
    const int c0   = wid * 4;            // 4 channels per wave

    const float* xb = x + (size_t)b * CDIM * LDIM;

    // P1: load x tile with circular halo, apply ELU
    for (int idx = tid; idx < CDIM * (TL + 2); idx += 1024) {
        int i   = idx / (TL + 2);
        int col = idx - i * (TL + 2);
        int l   = (l0 + col - 1 + LDIM) & (LDIM - 1);
        float t = xb[i * LDIM + l];
        xe[i][col] = t > 0.f ? t : expm1f(t);
    }
    __syncthreads();

    // P2: conv3. lane = position; 4 out-channels; weights via float4 VMEM.
    const float4* cw4 = (const float4*)cwT;
    float hacc[4];
#pragma unroll
    for (int j = 0; j < 4; ++j) hacc[j] = conv_b[c0 + j];

    for (int i4 = 0; i4 < 16; ++i4) {
        const int i0 = i4 * 4;
        float xv[12];
#pragma unroll
        for (int di = 0; di < 4; ++di) {
            xv[di * 3 + 0] = xe[i0 + di][lane];
            xv[di * 3 + 1] = xe[i0 + di][lane + 1];
            xv[di * 3 + 2] = xe[i0 + di][lane + 2];
        }
#pragma unroll
        for (int jj = 0; jj < 4; ++jj) {
            float4 w[4];
#pragma unroll
            for (int di = 0; di < 4; ++di)
                w[di] = cw4[((size_t)(i4 * 64 + c0 + jj)) * 4 + di];
            float a = hacc[jj];
#pragma unroll
            for (int di = 0; di < 4; ++di)
                a = fmaf(w[di].x, xv[di * 3 + 0],
                    fmaf(w[di].y, xv[di * 3 + 1],
                    fmaf(w[di].z, xv[di * 3 + 2], a)));
            hacc[jj] = a;
        }
    }
#pragma unroll
    for (int j = 0; j < 4; ++j) hs[c0 + j][lane] = hacc[j];
    __syncthreads();

    // P3: QKV. Weight rows as float4 VMEM; h streamed from LDS.
    const float4* wq4 = (const float4*)wq;
    const float4* wk4 = (const float4*)wk;
    const float4* wv4 = (const float4*)wv;
    float qa[4], ka[4], va[4];
#pragma unroll
    for (int j = 0; j < 4; ++j) {
        qa[j] = bq[c0 + j];
        ka[j] = bk[c0 + j];
        va[j] = bv[c0 + j];
    }
    for (int i4 = 0; i4 < 16; ++i4) {
        float h4[4];
#pragma unroll
        for (int di = 0; di < 4; ++di) h4[di] = hs[i4 * 4 + di][lane];
#pragma unroll
        for (int jj = 0; jj < 4; ++jj) {
            const int c = c0 + jj;
            float4 aq = wq4[c * 16 + i4];
            float4 ak = wk4[c * 16 + i4];
            float4 av = wv4[c * 16 + i4];
            qa[jj] = fmaf(aq.x, h4[0], fmaf(aq.y, h4[1],
                     fmaf(aq.z, h4[2], fmaf(aq.w, h4[3], qa[jj]))));
            ka[jj] = fmaf(ak.x, h4[0], fmaf(ak.y, h4[1],
                     fmaf(ak.z, h4[2], fmaf(ak.w, h4[3], ka[jj]))));
            va[jj] = fmaf(av.x, h4[0], fmaf(av.y, h4[1],
                     fmaf(av.z, h4[2], fmaf(av.w, h4[3], va[jj]))));
        }
    }
    *reinterpret_cast<float4*>(&qsT[lane][c0]) = make_float4(qa[0], qa[1], qa[2], qa[3]);
    *reinterpret_cast<float4*>(&vsT[lane][c0]) = make_float4(va[0], va[1], va[2], va[3]);
#pragma unroll
    for (int j = 0; j < 4; ++j)
        k_ws[((size_t)b * CDIM + c0 + j) * LDIM + l0 + lane] = ka[j];
    __syncthreads();

    // P4: partial M[c][c'] = sum_l v[c][l]*q[c'][l]; thread owns 1x4 tile.
    const int cv  = tid >> 4;         // 0..63
    const int cq0 = (tid & 15) * 4;   // 0..60 step 4 (16B aligned)
    float m0 = 0.f, m1 = 0.f, m2 = 0.f, m3 = 0.f;
    for (int l = 0; l < TL; ++l) {
        const float  vv = vsT[l][cv];
        const float4 qq = *reinterpret_cast<const float4*>(&qsT[l][cq0]);
        m0 = fmaf(vv, qq.x, m0);
        m1 = fmaf(vv, qq.y, m1);
        m2 = fmaf(vv, qq.z, m2);
        m3 = fmaf(vv, qq.w, m3);
    }
    float4* Pb = (float4*)(P_ws + ((size_t)b * NBLK + blockIdx.x) * CDIM * CDIM);
    Pb[cv * (CDIM / 4) + (cq0 >> 2)] = make_float4(m0, m1, m2, m3);
}

// ---------------------------------------------------------------------------
// Kernel 1b: reduce partials -> M[b][c][c'].  16 blocks x 256 threads.
// 4 independent accumulators -> 4 outstanding load groups (latency).
// ---------------------------------------------------------------------------
__global__ __launch_bounds__(256) void k_reduceM(
    const float* __restrict__ P_ws, float* __restrict__ M_ws)
{
    const int b  = blockIdx.x >> 2;
    const int e4 = (blockIdx.x & 3) * 256 + threadIdx.x;
    const float4* Pf4 = (const float4*)P_ws + (size_t)b * NBLK * (CDIM * CDIM / 4);
    float4 s0 = make_float4(0, 0, 0, 0), s1 = s0, s2 = s0, s3 = s0;
    for (int blk = 0; blk < NBLK; blk += 4) {
        float4 p0 = Pf4[(size_t)(blk + 0) * (CDIM * CDIM / 4) + e4];
        float4 p1 = Pf4[(size_t)(blk + 1) * (CDIM * CDIM / 4) + e4];
        float4 p2 = Pf4[(size_t)(blk + 2) * (CDIM * CDIM / 4) + e4];
        float4 p3 = Pf4[(size_t)(blk + 3) * (CDIM * CDIM / 4) + e4];
        s0.x += p0.x; s0.y += p0.y; s0.z += p0.z; s0.w += p0.w;
        s1.x += p1.x; s1.y += p1.y; s1.z += p1.z; s1.w += p1.w;
        s2.x += p2.x; s2.y += p2.y; s2.z += p2.z; s2.w += p2.w;
        s3.x += p3.x; s3.y += p3.y; s3.z += p3.z; s3.w += p3.w;
    }
    float4 s = make_float4((s0.x + s1.x) + (s2.x + s3.x),
                           (s0.y + s1.y) + (s2.y + s3.y),
                           (s0.z + s1.z) + (s2.z + s3.z),
                           (s0.w + s1.w) + (s2.w + s3.w));
    ((float4*)M_ws)[(size_t)b * (CDIM * CDIM / 4) + e4] = s;
}

// ---------------------------------------------------------------------------
// Kernel 2: y = M k + x; BN partial sums. block 1024 = 16 waves, 4 ch/wave.
// M (16 KB) staged into LDS once; read as wave-uniform b128 broadcasts.
// ---------------------------------------------------------------------------
__global__ __launch_bounds__(1024, 4) void k_spatial(
    const float* __restrict__ x, const float* __restrict__ k_ws,
    const float* __restrict__ M_ws, float* __restrict__ y_ws,
    float* __restrict__ spB)
{
    __shared__ float kl[CDIM][TL + 1];
    __shared__ alignas(16) float Ms[CDIM][CDIM];
    const int b    = blockIdx.y;
    const int l0   = blockIdx.x * TL;
    const int tid  = threadIdx.x;
    const int lane = tid & 63;
    const int wid  = tid >> 6;           // 0..15
    const int c0   = wid * 4;

    // stage M (one float4 per thread) and k tile
    ((float4*)Ms)[tid] = ((const float4*)M_ws)[(size_t)b * (CDIM * CDIM / 4) + tid];
    for (int idx = tid; idx < CDIM * TL; idx += 1024) {
        int i = idx >> 6, col = idx & 63;
        kl[i][col] = k_ws[((size_t)b * CDIM + i) * LDIM + l0 + col];
    }
    __syncthreads();

    float acc[4];
#pragma unroll
    for (int j = 0; j < 4; ++j)
        acc[j] = x[((size_t)b * CDIM + c0 + j) * LDIM + l0 + lane];

    for (int i4 = 0; i4 < 16; ++i4) {
        float kv0 = kl[i4 * 4 + 0][lane];
        float kv1 = kl[i4 * 4 + 1][lane];
        float kv2 = kl[i4 * 4 + 2][lane];
        float kv3 = kl[i4 * 4 + 3][lane];
#pragma unroll
        for (int j = 0; j < 4; ++j) {
            // wave-uniform address -> LDS broadcast, conflict-free
            float4 m4 = *reinterpret_cast<const float4*>(&Ms[c0 + j][i4 * 4]);
            float a = acc[j];
            a = fmaf(m4.x, kv0, a);
            a = fmaf(m4.y, kv1, a);
            a = fmaf(m4.z, kv2, a);
            a = fmaf(m4.w, kv3, a);
            acc[j] = a;
        }
    }

#pragma unroll
    for (int j = 0; j < 4; ++j)
        y_ws[((size_t)b * CDIM + c0 + j) * LDIM + l0 + lane] = acc[j];

    // per-channel partial sums -> per-block slot (two-stage, no atomics)
    const int blk = blockIdx.y * NBLK + blockIdx.x;
#pragma unroll
    for (int j = 0; j < 4; ++j) {
        float s = acc[j], s2 = acc[j] * acc[j];
        for (int off = 32; off; off >>= 1) {
            s  += __shfl_down(s, off);
            s2 += __shfl_down(s2, off);
        }
        if (lane == 0) {
            spB[(size_t)blk * (2 * CDIM) + c0 + j] = s;
            spB[(size_t)blk * (2 * CDIM) + CDIM + c0 + j] = s2;
        }
    }
}

// ---------------------------------------------------------------------------
// Kernel 2b: reduce BN partials. 512 threads: col x row-quarter, LDS combine.
// ---------------------------------------------------------------------------
__global__ __launch_bounds__(512) void k_reduceS(
    const float* __restrict__ spB, float* __restrict__ sums)
{
    __shared__ float red[4][128];
    const int t = threadIdx.x & 127;
    const int q = threadIdx.x >> 7;      // 0..3, 64 rows each
    float s0 = 0.f, s1 = 0.f, s2 = 0.f, s3 = 0.f;
    const int r0 = q * 64;
    for (int r = r0; r < r0 + 64; r += 4) {
        s0 += spB[(r + 0) * (2 * CDIM) + t];
        s1 += spB[(r + 1) * (2 * CDIM) + t];
        s2 += spB[(r + 2) * (2 * CDIM) + t];
        s3 += spB[(r + 3) * (2 * CDIM) + t];
    }
    red[q][t] = (s0 + s1) + (s2 + s3);
    __syncthreads();
    if (threadIdx.x < 128)
        sums[t] = (red[0][t] + red[1][t]) + (red[2][t] + red[3][t]);
}

// ---------------------------------------------------------------------------
// Kernel 3: BatchNorm1d (training stats) applied elementwise, float4
// ---------------------------------------------------------------------------
__global__ __launch_bounds__(256) void k_norm(
    const float* __restrict__ y_ws, const float* __restrict__ sums,
    const float* __restrict__ gamma, const float* __restrict__ beta,
    float* __restrict__ out)
{
    const int idx = blockIdx.x * 256 + threadIdx.x;        // float4 index
    const int c   = (idx >> 10) & (CDIM - 1);
    const float inv = 1.f / (float)(NB * LDIM);
    float s    = sums[c];
    float s2   = sums[CDIM + c];
    float mean = s * inv;
    float var  = fmaf(-mean, mean, s2 * inv);
    float rstd = 1.f / sqrtf(var + EPS);
    float g    = gamma[c] * rstd;
    float bb   = fmaf(-mean, g, beta[c]);

    float4 v = ((const float4*)y_ws)[idx];
    float4 o;
    o.x = fmaf(v.x, g, bb);
    o.y = fmaf(v.y, g, bb);
    o.z = fmaf(v.z, g, bb);
    o.w = fmaf(v.w, g, bb);
    ((float4*)out)[idx] = o;
}

// ---------------------------------------------------------------------------
extern "C" void kernel_launch(void* const* d_in, const int* in_sizes, int n_in,
                              void* d_out, int out_size, void* d_ws, size_t ws_size,
                              hipStream_t stream)
{
    const float* x      = (const float*)d_in[0];
    const float* conv_w = (const float*)d_in[1];
    const float* conv_b = (const float*)d_in[2];
    const float* wq     = (const float*)d_in[3];
    const float* bq     = (const float*)d_in[4];
    const float* wk     = (const float*)d_in[5];
    const float* bk     = (const float*)d_in[6];
    const float* wv     = (const float*)d_in[7];
    const float* bv     = (const float*)d_in[8];
    const float* gamma  = (const float*)d_in[9];
    const float* beta   = (const float*)d_in[10];

    float* ws   = (float*)d_ws;
    float* k_ws = ws + K_OFF;
    float* y_ws = ws + Y_OFF;
    float* P_ws = ws + P_OFF;
    float* M_ws = ws + M_OFF;
    float* cwT  = ws + CW_OFF;
    float* spB  = ws + SP_OFF;
    float* sums = ws + S_OFF;

    dim3 grid(NBLK, NB);
    k_prep<<<64, 256, 0, stream>>>(conv_w, cwT);
    k_front<<<grid, 1024, 0, stream>>>(x, cwT, conv_b, wq, bq, wk, bk,
                                       wv, bv, k_ws, P_ws);
    k_reduceM<<<16, 256, 0, stream>>>(P_ws, M_ws);
    k_spatial<<<grid, 1024, 0, stream>>>(x, k_ws, M_ws, y_ws, spB);
    k_reduceS<<<1, 512, 0, stream>>>(spB, sums);

    const int n4 = NB * CDIM * LDIM / 4;
    k_norm<<<n4 / 256, 256, 0, stream>>>(y_ws, sums, gamma, beta, (float*)d_out);
}

// Round 7
// 123.076 us; speedup vs baseline: 1.9162x; 1.2954x over previous
//
#include <hip/hip_runtime.h>
#include <math.h>

#define LDIM 4096
#define CDIM 64
#define NB 4
#define TL 64
#define NBLK (LDIM / TL)          // 64 L-tiles per batch
#define NBLOCKS (NB * NBLK)       // 256
#define EPS 1e-5f
#define XS 68                     // LDS row stride (17 float4 -> 16B-aligned rows)

// workspace layout (float offsets) — total ~12.9 MB
#define K_OFF 0                                   // k: [B][C][L]
#define Y_OFF (NB * CDIM * LDIM)                  // y: [B][C][L]
#define P_OFF (2 * NB * CDIM * LDIM)              // M partials: [NBLOCKS][C*C]
#define M_OFF (P_OFF + NBLOCKS * CDIM * CDIM)     // M: [B][C*C]
#define CW_OFF (M_OFF + NB * CDIM * CDIM)         // conv_w transposed: 16*64*16
#define SP_OFF (CW_OFF + 16 * CDIM * 16)          // BN partials: [NBLOCKS][2*C]
#define S_OFF (SP_OFF + NBLOCKS * 2 * CDIM)       // reduced BN sums: [2*C]

__device__ __forceinline__ float elu1(float t) { return t > 0.f ? t : expm1f(t); }

// ---------------------------------------------------------------------------
// Kernel 0: transpose conv_w [c][i][3] -> cw4[(i4*64+c)*4+di] = w[c][i4*4+di][0..2],0
// ---------------------------------------------------------------------------
__global__ __launch_bounds__(256) void k_prep(
    const float* __restrict__ cw, float* __restrict__ cwT)
{
    int idx = blockIdx.x * 256 + threadIdx.x;      // 0..16383
    int t  = idx & 3;
    int di = (idx >> 2) & 3;
    int c  = (idx >> 4) & 63;
    int i4 = idx >> 10;
    float v = (t < 3) ? cw[(c * CDIM + i4 * 4 + di) * 3 + t] : 0.f;
    cwT[idx] = v;
}

// ---------------------------------------------------------------------------
// Kernel 1: ELU -> circular conv3 -> QKV -> (k to global, partial M = v q^T)
// grid (NBLK, NB), block 1024. Thread = (1 out-channel c, 4 positions p0..p0+3):
// each weight float4 feeds 12-16 FMAs (R5: 3-4) -> 4x fewer VMEM loads,
// and all LDS tile traffic is aligned b128 on stride-68 rows (2-way max).
// ---------------------------------------------------------------------------
__global__ __launch_bounds__(1024, 4) void k_front(
    const float* __restrict__ x,
    const float* __restrict__ cwT, const float* __restrict__ conv_b,
    const float* __restrict__ wq, const float* __restrict__ bq,
    const float* __restrict__ wk, const float* __restrict__ bk,
    const float* __restrict__ wv, const float* __restrict__ bv,
    float* __restrict__ k_ws, float* __restrict__ P_ws)
{
    __shared__ alignas(16) float xe[CDIM][XS];   // col = pos+1 (1..64), halo 0,65
    __shared__ alignas(16) float hs[CDIM][XS];   // col = pos
    __shared__ alignas(16) float qsT[TL][XS];    // [pos][c]
    __shared__ alignas(16) float vsT[TL][XS];

    const int b   = blockIdx.y;
    const int l0  = blockIdx.x * TL;
    const int tid = threadIdx.x;
    const int c   = tid >> 4;          // out-channel 0..63
    const int p0  = (tid & 15) << 2;   // position group 0..60

    const float* xb = x + (size_t)b * CDIM * LDIM;

    // P1: stage elu(x) tile (col = pos+1) + circular halo cols 0 and 65
    {
        float4 xv = *reinterpret_cast<const float4*>(xb + (size_t)c * LDIM + l0 + p0);
        xe[c][p0 + 1] = elu1(xv.x);
        xe[c][p0 + 2] = elu1(xv.y);
        xe[c][p0 + 3] = elu1(xv.z);
        xe[c][p0 + 4] = elu1(xv.w);
        if (tid < CDIM)
            xe[tid][0] = elu1(xb[(size_t)tid * LDIM + ((l0 - 1) & (LDIM - 1))]);
        else if (tid < 2 * CDIM)
            xe[tid - CDIM][TL + 1] =
                elu1(xb[(size_t)(tid - CDIM) * LDIM + ((l0 + TL) & (LDIM - 1))]);
    }
    __syncthreads();

    // P2: conv3. Per i4: 4 float4 weight loads (64B contiguous) feed 48 FMAs.
    const float4* cw4 = (const float4*)cwT;
    float hacc[4];
    {
        float cb = conv_b[c];
        hacc[0] = hacc[1] = hacc[2] = hacc[3] = cb;
    }
    for (int i4 = 0; i4 < 16; ++i4) {
        float4 w[4];
#pragma unroll
        for (int di = 0; di < 4; ++di)
            w[di] = cw4[(size_t)(i4 * 64 + c) * 4 + di];
#pragma unroll
        for (int di = 0; di < 4; ++di) {
            const float* xr = &xe[i4 * 4 + di][p0];
            float4 a  = *reinterpret_cast<const float4*>(xr);      // cols p0..p0+3
            float2 e2 = *reinterpret_cast<const float2*>(xr + 4);  // cols p0+4,p0+5
            hacc[0] = fmaf(w[di].x, a.x, fmaf(w[di].y, a.y, fmaf(w[di].z, a.z,  hacc[0])));
            hacc[1] = fmaf(w[di].x, a.y, fmaf(w[di].y, a.z, fmaf(w[di].z, a.w,  hacc[1])));
            hacc[2] = fmaf(w[di].x, a.z, fmaf(w[di].y, a.w, fmaf(w[di].z, e2.x, hacc[2])));
            hacc[3] = fmaf(w[di].x, a.w, fmaf(w[di].y, e2.x, fmaf(w[di].z, e2.y, hacc[3])));
        }
    }
    *reinterpret_cast<float4*>(&hs[c][p0]) =
        make_float4(hacc[0], hacc[1], hacc[2], hacc[3]);
    __syncthreads();

    // P3: QKV. Per i4: 3 weight float4 + 4 b128 h reads feed 48 FMAs.
    const float4* wq4 = (const float4*)wq;
    const float4* wk4 = (const float4*)wk;
    const float4* wv4 = (const float4*)wv;
    float qa[4], ka[4], va[4];
    {
        float t;
        t = bq[c]; qa[0] = qa[1] = qa[2] = qa[3] = t;
        t = bk[c]; ka[0] = ka[1] = ka[2] = ka[3] = t;
        t = bv[c]; va[0] = va[1] = va[2] = va[3] = t;
    }
    for (int i4 = 0; i4 < 16; ++i4) {
        float4 aq = wq4[c * 16 + i4];
        float4 ak = wk4[c * 16 + i4];
        float4 av = wv4[c * 16 + i4];
        float4 h0 = *reinterpret_cast<const float4*>(&hs[i4 * 4 + 0][p0]);
        float4 h1 = *reinterpret_cast<const float4*>(&hs[i4 * 4 + 1][p0]);
        float4 h2 = *reinterpret_cast<const float4*>(&hs[i4 * 4 + 2][p0]);
        float4 h3 = *reinterpret_cast<const float4*>(&hs[i4 * 4 + 3][p0]);
        qa[0] = fmaf(aq.x, h0.x, fmaf(aq.y, h1.x, fmaf(aq.z, h2.x, fmaf(aq.w, h3.x, qa[0]))));
        qa[1] = fmaf(aq.x, h0.y, fmaf(aq.y, h1.y, fmaf(aq.z, h2.y, fmaf(aq.w, h3.y, qa[1]))));
        qa[2] = fmaf(aq.x, h0.z, fmaf(aq.y, h1.z, fmaf(aq.z, h2.z, fmaf(aq.w, h3.z, qa[2]))));
        qa[3] = fmaf(aq.x, h0.w, fmaf(aq.y, h1.w, fmaf(aq.z, h2.w, fmaf(aq.w, h3.w, qa[3]))));
        ka[0] = fmaf(ak.x, h0.x, fmaf(ak.y, h1.x, fmaf(ak.z, h2.x, fmaf(ak.w, h3.x, ka[0]))));
        ka[1] = fmaf(ak.x, h0.y, fmaf(ak.y, h1.y, fmaf(ak.z, h2.y, fmaf(ak.w, h3.y, ka[1]))));
        ka[2] = fmaf(ak.x, h0.z, fmaf(ak.y, h1.z, fmaf(ak.z, h2.z, fmaf(ak.w, h3.z, ka[2]))));
        ka[3] = fmaf(ak.x, h0.w, fmaf(ak.y, h1.w, fmaf(ak.z, h2.w, fmaf(ak.w, h3.w, ka[3]))));
        va[0] = fmaf(av.x, h0.x, fmaf(av.y, h1.x, fmaf(av.z, h2.x, fmaf(av.w, h3.x, va[0]))));
        va[1] = fmaf(av.x, h0.y, fmaf(av.y, h1.y, fmaf(av.z, h2.y, fmaf(av.w, h3.y, va[1]))));
        va[2] = fmaf(av.x, h0.z, fmaf(av.y, h1.z, fmaf(av.z, h2.z, fmaf(av.w, h3.z, va[2]))));
        va[3] = fmaf(av.x, h0.w, fmaf(av.y, h1.w, fmaf(av.z, h2.w, fmaf(av.w, h3.w, va[3]))));
    }
    *reinterpret_cast<float4*>(k_ws + ((size_t)b * CDIM + c) * LDIM + l0 + p0) =
        make_float4(ka[0], ka[1], ka[2], ka[3]);
    qsT[p0 + 0][c] = qa[0]; qsT[p0 + 1][c] = qa[1];
    qsT[p0 + 2][c] = qa[2]; qsT[p0 + 3][c] = qa[3];
    vsT[p0 + 0][c] = va[0]; vsT[p0 + 1][c] = va[1];
    vsT[p0 + 2][c] = va[2]; vsT[p0 + 3][c] = va[3];
    __syncthreads();

    // P4: partial M[cv][cq] = sum_l v[cv][l]*q[cq][l]; thread owns 1x4 tile.
    const int cv  = tid >> 4;         // 0..63
    const int cq0 = (tid & 15) * 4;   // 0..60
    float m0 = 0.f, m1 = 0.f, m2 = 0.f, m3 = 0.f;
    for (int l = 0; l < TL; ++l) {
        const float  vv = vsT[l][cv];
        const float4 qq = *reinterpret_cast<const float4*>(&qsT[l][cq0]);
        m0 = fmaf(vv, qq.x, m0);
        m1 = fmaf(vv, qq.y, m1);
        m2 = fmaf(vv, qq.z, m2);
        m3 = fmaf(vv, qq.w, m3);
    }
    float4* Pb = (float4*)(P_ws + ((size_t)b * NBLK + blockIdx.x) * CDIM * CDIM);
    Pb[cv * (CDIM / 4) + (cq0 >> 2)] = make_float4(m0, m1, m2, m3);
}

// ---------------------------------------------------------------------------
// Kernel 1b: reduce partials -> M[b][c][c'].  16 blocks x 256 threads.
// ---------------------------------------------------------------------------
__global__ __launch_bounds__(256) void k_reduceM(
    const float* __restrict__ P_ws, float* __restrict__ M_ws)
{
    const int b  = blockIdx.x >> 2;
    const int e4 = (blockIdx.x & 3) * 256 + threadIdx.x;
    const float4* Pf4 = (const float4*)P_ws + (size_t)b * NBLK * (CDIM * CDIM / 4);
    float4 s0 = make_float4(0, 0, 0, 0), s1 = s0, s2 = s0, s3 = s0;
    for (int blk = 0; blk < NBLK; blk += 4) {
        float4 p0 = Pf4[(size_t)(blk + 0) * (CDIM * CDIM / 4) + e4];
        float4 p1 = Pf4[(size_t)(blk + 1) * (CDIM * CDIM / 4) + e4];
        float4 p2 = Pf4[(size_t)(blk + 2) * (CDIM * CDIM / 4) + e4];
        float4 p3 = Pf4[(size_t)(blk + 3) * (CDIM * CDIM / 4) + e4];
        s0.x += p0.x; s0.y += p0.y; s0.z += p0.z; s0.w += p0.w;
        s1.x += p1.x; s1.y += p1.y; s1.z += p1.z; s1.w += p1.w;
        s2.x += p2.x; s2.y += p2.y; s2.z += p2.z; s2.w += p2.w;
        s3.x += p3.x; s3.y += p3.y; s3.z += p3.z; s3.w += p3.w;
    }
    float4 s = make_float4((s0.x + s1.x) + (s2.x + s3.x),
                           (s0.y + s1.y) + (s2.y + s3.y),
                           (s0.z + s1.z) + (s2.z + s3.z),
                           (s0.w + s1.w) + (s2.w + s3.w));
    ((float4*)M_ws)[(size_t)b * (CDIM * CDIM / 4) + e4] = s;
}

// ---------------------------------------------------------------------------
// Kernel 2: y = M k + x; BN partials. Thread = (1 channel, 4 positions).
// Per i4: 1 Ms b128 + 4 kl b128 feed 16 FMAs; all global access float4.
// ---------------------------------------------------------------------------
__global__ __launch_bounds__(1024, 4) void k_spatial(
    const float* __restrict__ x, const float* __restrict__ k_ws,
    const float* __restrict__ M_ws, float* __restrict__ y_ws,
    float* __restrict__ spB)
{
    __shared__ alignas(16) float kl[CDIM][XS];
    __shared__ alignas(16) float Ms[CDIM][XS];   // stride 68 kills same-bank alias
    const int b   = blockIdx.y;
    const int l0  = blockIdx.x * TL;
    const int tid = threadIdx.x;
    const int c   = tid >> 4;
    const int p0  = (tid & 15) << 2;

    *reinterpret_cast<float4*>(&Ms[c][p0]) =
        ((const float4*)M_ws)[(size_t)b * (CDIM * CDIM / 4) + tid];
    *reinterpret_cast<float4*>(&kl[c][p0]) =
        *reinterpret_cast<const float4*>(k_ws + ((size_t)b * CDIM + c) * LDIM + l0 + p0);
    __syncthreads();

    float4 acc = *reinterpret_cast<const float4*>(
        x + ((size_t)b * CDIM + c) * LDIM + l0 + p0);
    for (int i4 = 0; i4 < 16; ++i4) {
        float4 mv = *reinterpret_cast<const float4*>(&Ms[c][i4 * 4]);
        float4 k0 = *reinterpret_cast<const float4*>(&kl[i4 * 4 + 0][p0]);
        float4 k1 = *reinterpret_cast<const float4*>(&kl[i4 * 4 + 1][p0]);
        float4 k2 = *reinterpret_cast<const float4*>(&kl[i4 * 4 + 2][p0]);
        float4 k3 = *reinterpret_cast<const float4*>(&kl[i4 * 4 + 3][p0]);
        acc.x = fmaf(mv.x, k0.x, fmaf(mv.y, k1.x, fmaf(mv.z, k2.x, fmaf(mv.w, k3.x, acc.x))));
        acc.y = fmaf(mv.x, k0.y, fmaf(mv.y, k1.y, fmaf(mv.z, k2.y, fmaf(mv.w, k3.y, acc.y))));
        acc.z = fmaf(mv.x, k0.z, fmaf(mv.y, k1.z, fmaf(mv.z, k2.z, fmaf(mv.w, k3.z, acc.z))));
        acc.w = fmaf(mv.x, k0.w, fmaf(mv.y, k1.w, fmaf(mv.z, k2.w, fmaf(mv.w, k3.w, acc.w))));
    }
    *reinterpret_cast<float4*>(y_ws + ((size_t)b * CDIM + c) * LDIM + l0 + p0) = acc;

    // BN partial sums: reduce over the 16 lanes sharing channel c
    const int blk = blockIdx.y * NBLK + blockIdx.x;
    float s  = (acc.x + acc.y) + (acc.z + acc.w);
    float s2 = fmaf(acc.x, acc.x, fmaf(acc.y, acc.y,
               fmaf(acc.z, acc.z, acc.w * acc.w)));
    for (int off = 8; off; off >>= 1) {
        s  += __shfl_down(s, off);
        s2 += __shfl_down(s2, off);
    }
    if ((tid & 15) == 0) {
        spB[(size_t)blk * (2 * CDIM) + c] = s;
        spB[(size_t)blk * (2 * CDIM) + CDIM + c] = s2;
    }
}

// ---------------------------------------------------------------------------
// Kernel 2b: reduce BN partials. 512 threads: col x row-quarter, LDS combine.
// ---------------------------------------------------------------------------
__global__ __launch_bounds__(512) void k_reduceS(
    const float* __restrict__ spB, float* __restrict__ sums)
{
    __shared__ float red[4][128];
    const int t = threadIdx.x & 127;
    const int q = threadIdx.x >> 7;      // 0..3, 64 rows each
    float s0 = 0.f, s1 = 0.f, s2 = 0.f, s3 = 0.f;
    const int r0 = q * 64;
    for (int r = r0; r < r0 + 64; r += 4) {
        s0 += spB[(r + 0) * (2 * CDIM) + t];
        s1 += spB[(r + 1) * (2 * CDIM) + t];
        s2 += spB[(r + 2) * (2 * CDIM) + t];
        s3 += spB[(r + 3) * (2 * CDIM) + t];
    }
    red[q][t] = (s0 + s1) + (s2 + s3);
    __syncthreads();
    if (threadIdx.x < 128)
        sums[t] = (red[0][t] + red[1][t]) + (red[2][t] + red[3][t]);
}

// ---------------------------------------------------------------------------
// Kernel 3: BatchNorm1d (training stats) applied elementwise, float4
// ---------------------------------------------------------------------------
__global__ __launch_bounds__(256) void k_norm(
    const float* __restrict__ y_ws, const float* __restrict__ sums,
    const float* __restrict__ gamma, const float* __restrict__ beta,
    float* __restrict__ out)
{
    const int idx = blockIdx.x * 256 + threadIdx.x;        // float4 index
    const int c   = (idx >> 10) & (CDIM - 1);
    const float inv = 1.f / (float)(NB * LDIM);
    float s    = sums[c];
    float s2   = sums[CDIM + c];
    float mean = s * inv;
    float var  = fmaf(-mean, mean, s2 * inv);
    float rstd = 1.f / sqrtf(var + EPS);
    float g    = gamma[c] * rstd;
    float bb   = fmaf(-mean, g, beta[c]);

    float4 v = ((const float4*)y_ws)[idx];
    float4 o;
    o.x = fmaf(v.x, g, bb);
    o.y = fmaf(v.y, g, bb);
    o.z = fmaf(v.z, g, bb);
    o.w = fmaf(v.w, g, bb);
    ((float4*)out)[idx] = o;
}

// ---------------------------------------------------------------------------
extern "C" void kernel_launch(void* const* d_in, const int* in_sizes, int n_in,
                              void* d_out, int out_size, void* d_ws, size_t ws_size,
                              hipStream_t stream)
{
    const float* x      = (const float*)d_in[0];
    const float* conv_w = (const float*)d_in[1];
    const float* conv_b = (const float*)d_in[2];
    const float* wq     = (const float*)d_in[3];
    const float* bq     = (const float*)d_in[4];
    const float* wk     = (const float*)d_in[5];
    const float* bk     = (const float*)d_in[6];
    const float* wv     = (const float*)d_in[7];
    const float* bv     = (const float*)d_in[8];
    const float* gamma  = (const float*)d_in[9];
    const float* beta   = (const float*)d_in[10];

    float* ws   = (float*)d_ws;
    float* k_ws = ws + K_OFF;
    float* y_ws = ws + Y_OFF;
    float* P_ws = ws + P_OFF;
    float* M_ws = ws + M_OFF;
    float* cwT  = ws + CW_OFF;
    float* spB  = ws + SP_OFF;
    float* sums = ws + S_OFF;

    dim3 grid(NBLK, NB);
    k_prep<<<64, 256, 0, stream>>>(conv_w, cwT);
    k_front<<<grid, 1024, 0, stream>>>(x, cwT, conv_b, wq, bq, wk, bk,
                                       wv, bv, k_ws, P_ws);
    k_reduceM<<<16, 256, 0, stream>>>(P_ws, M_ws);
    k_spatial<<<grid, 1024, 0, stream>>>(x, k_ws, M_ws, y_ws, spB);
    k_reduceS<<<1, 512, 0, stream>>>(spB, sums);

    const int n4 = NB * CDIM * LDIM / 4;
    k_norm<<<n4 / 256, 256, 0, stream>>>(y_ws, sums, gamma, beta, (float*)d_out);
}